// Round 3
// baseline (5499.170 us; speedup 1.0000x reference)
//
#include <hip/hip_runtime.h>
#include <utility>

namespace {

constexpr int H   = 64;
constexpr int NIN = 21;
constexpr int T   = 3000;
constexpr int NB  = 2;     // batches per block
constexpr int G   = 256;   // 4*H

__device__ __forceinline__ float sigm(float v) {
    return 1.0f / (1.0f + __expf(-v));
}
__device__ __forceinline__ float tanh_fast(float v) {
    float e = __expf(2.0f * v);
    return 1.0f - 2.0f / (e + 1.0f);
}

// DPP row rotate-right by J within 16-lane rows.
// HW semantics: out[lane] = in[(lane & 48) | ((lane - J) & 15)]
template<int J>
__device__ __forceinline__ float rotj(float v) {
    if constexpr (J == 0) {
        return v;
    } else {
        int r = __builtin_amdgcn_update_dpp(0, __float_as_int(v), 0x120 + J, 0xF, 0xF, true);
        return __int_as_float(r);
    }
}

template<int OFS, int N, size_t... J>
__device__ __forceinline__ void dot16i(const float (&w)[N], float h0, float h1,
                                       float& a0, float& a1, std::index_sequence<J...>) {
    (((a0 = fmaf(w[OFS + (int)J], rotj<(int)J>(h0), a0)),
      (a1 = fmaf(w[OFS + (int)J], rotj<(int)J>(h1), a1))), ...);
}

// acc_b += dot(w[OFS..OFS+15], h-values reachable by rotating hq_b)
template<int OFS, int N>
__device__ __forceinline__ void dot16(const float (&w)[N], float h0, float h1,
                                      float& a0, float& a1) {
    dot16i<OFS>(w, h0, h1, a0, a1, std::make_index_sequence<16>{});
}

__launch_bounds__(768, 3)
__global__ void lstm_dpp(const float* __restrict__ x,
                         const float* __restrict__ Wih0, const float* __restrict__ Whh0,
                         const float* __restrict__ bih0, const float* __restrict__ bhh0,
                         const float* __restrict__ Wih1, const float* __restrict__ Whh1,
                         const float* __restrict__ bih1, const float* __restrict__ bhh1,
                         const float* __restrict__ Wfc,  const float* __restrict__ bfc,
                         float* __restrict__ out)
{
    const int tid  = threadIdx.x;
    const int lane = tid & 63;
    const int wid  = tid >> 6;
    const int b0   = blockIdx.x * NB;

    // roles: waves 0-3 = layer0 gates (and all pointwise), 4-7 = Wih1 rows (+x staging),
    //        8-11 = Whh1 rows
    const bool isA = (wid < 4);
    const bool isB = (wid >= 4 && wid < 8);
    const int  g   = tid & 255;        // gate row within role

    __shared__ float xs[4][NB][32];    // x staged 2 steps ahead, padded 21->32
    __shared__ float a0s[NB][G];       // layer0 pre-activations
    __shared__ float p1x[NB][G];       // layer1 Wih1*h1 partial
    __shared__ float p1h[NB][G];       // layer1 Whh1*h2 partial (+bias1)
    __shared__ float h1s[NB][H];
    __shared__ float h2s[NB][H];

    // ---- per-lane weight gather, permuted for the DPP access pattern ----
    // rotj<J> delivers h[16m + ((lane-J)&15)], so weight slot J must hold
    // rowW[16m + ((lane-J)&15)].
    float wH[64];
    float wX[32];
    float bias = 0.0f;
    {
        const float* rowH;
        if (isA)      rowH = Whh0 + g * 64;
        else if (isB) rowH = Wih1 + g * 64;
        else          rowH = Whh1 + g * 64;
        #pragma unroll
        for (int m = 0; m < 4; ++m)
            #pragma unroll
            for (int j = 0; j < 16; ++j)
                wH[m * 16 + j] = rowH[16 * m + ((lane - j) & 15)];

        if (isA) {
            #pragma unroll
            for (int m = 0; m < 2; ++m)
                #pragma unroll
                for (int j = 0; j < 16; ++j) {
                    int k = 16 * m + ((lane - j) & 15);
                    wX[m * 16 + j] = (k < NIN) ? Wih0[g * NIN + k] : 0.0f;
                }
            bias = bih0[g] + bhh0[g];
        } else {
            #pragma unroll
            for (int i = 0; i < 32; ++i) wX[i] = 0.0f;
            if (!isB) bias = bih1[g] + bhh1[g];
        }
    }

    // zero h buffers, stage x(t=0) and x(t=1)
    if (tid < NB * H) {
        (&h1s[0][0])[tid] = 0.0f;
        (&h2s[0][0])[tid] = 0.0f;
    }
    if ((wid == 4 || wid == 5) && lane < NIN)
        xs[0][wid - 4][lane] = x[((size_t)(b0 + (wid - 4)) * T + 0) * NIN + lane];
    if ((wid == 6 || wid == 7) && lane < NIN)
        xs[1][wid - 6][lane] = x[((size_t)(b0 + (wid - 6)) * T + 1) * NIN + lane];

    float hq1[NB][4];   // h1 replicated: hq1[b][m] = h1[b][16m + (lane&15)]
    float hq2[NB][4];
    #pragma unroll
    for (int b = 0; b < NB; ++b)
        #pragma unroll
        for (int m = 0; m < 4; ++m) { hq1[b][m] = 0.0f; hq2[b][m] = 0.0f; }

    float c_st = 0.0f;   // c-state: tid<128 -> layer0 c, tid 128..255 -> layer1 c
    __syncthreads();

    // Pipeline: iteration t computes layer0(t) and layer1(t-1).
    for (int t = 0; t <= T; ++t) {
        // ---------------- phase 1: matvec FMAs ----------------
        if (isA) {
            if (t < T) {
                float xq00 = xs[t & 3][0][lane & 15];
                float xq01 = xs[t & 3][0][16 + (lane & 15)];
                float xq10 = xs[t & 3][1][lane & 15];
                float xq11 = xs[t & 3][1][16 + (lane & 15)];
                float acc0 = bias, acc1 = bias;
                dot16<0 >(wH, hq1[0][0], hq1[1][0], acc0, acc1);
                dot16<16>(wH, hq1[0][1], hq1[1][1], acc0, acc1);
                dot16<32>(wH, hq1[0][2], hq1[1][2], acc0, acc1);
                dot16<48>(wH, hq1[0][3], hq1[1][3], acc0, acc1);
                dot16<0 >(wX, xq00, xq10, acc0, acc1);
                dot16<16>(wX, xq01, xq11, acc0, acc1);
                a0s[0][g] = acc0;
                a0s[1][g] = acc1;
            }
        } else if (isB) {
            // stage x(t+2) early; LDS-write after the FMAs (latency hidden)
            float xv = 0.0f;
            const int  bs = wid & 1;                       // wave4/6 -> b0, wave5/7 -> b1
            const bool st = (wid == 4 || wid == 5) && (t + 2 < T) && (lane < NIN);
            if (st) xv = x[((size_t)(b0 + bs) * T + (t + 2)) * NIN + lane];
            if (t > 0) {
                float acc0 = 0.0f, acc1 = 0.0f;
                dot16<0 >(wH, hq1[0][0], hq1[1][0], acc0, acc1);
                dot16<16>(wH, hq1[0][1], hq1[1][1], acc0, acc1);
                dot16<32>(wH, hq1[0][2], hq1[1][2], acc0, acc1);
                dot16<48>(wH, hq1[0][3], hq1[1][3], acc0, acc1);
                p1x[0][g] = acc0;
                p1x[1][g] = acc1;
            }
            if (st) xs[(t + 2) & 3][bs][lane] = xv;
        } else {
            if (t > 0) {
                float acc0 = bias, acc1 = bias;
                dot16<0 >(wH, hq2[0][0], hq2[1][0], acc0, acc1);
                dot16<16>(wH, hq2[0][1], hq2[1][1], acc0, acc1);
                dot16<32>(wH, hq2[0][2], hq2[1][2], acc0, acc1);
                dot16<48>(wH, hq2[0][3], hq2[1][3], acc0, acc1);
                p1h[0][g] = acc0;
                p1h[1][g] = acc1;
            }
        }
        __syncthreads();

        // ---------------- phase 2: pointwise ----------------
        if (tid < 128) {
            if (t < T) {                       // layer0 step t
                const int b = tid >> 6;
                const int u = lane;
                float gi = a0s[b][u];
                float gf = a0s[b][64 + u];
                float gg = a0s[b][128 + u];
                float go = a0s[b][192 + u];
                float i_ = sigm(gi), f_ = sigm(gf), g_ = tanh_fast(gg), o_ = sigm(go);
                c_st = fmaf(f_, c_st, i_ * g_);
                h1s[b][u] = o_ * tanh_fast(c_st);
            }
        } else if (tid < 256) {
            if (t > 0) {                       // layer1 step t-1
                const int b = (tid >> 6) & 1;
                const int u = lane;
                float gi = p1x[b][u]       + p1h[b][u];
                float gf = p1x[b][64 + u]  + p1h[b][64 + u];
                float gg = p1x[b][128 + u] + p1h[b][128 + u];
                float go = p1x[b][192 + u] + p1h[b][192 + u];
                float i_ = sigm(gi), f_ = sigm(gf), g_ = tanh_fast(gg), o_ = sigm(go);
                c_st = fmaf(f_, c_st, i_ * g_);
                h2s[b][u] = o_ * tanh_fast(c_st);
            }
        }
        __syncthreads();

        if (t == T) break;

        // ---------------- phase 3: redistribute h into rotation registers ----------------
        if (wid >= 8) {
            #pragma unroll
            for (int b = 0; b < NB; ++b)
                #pragma unroll
                for (int m = 0; m < 4; ++m)
                    hq2[b][m] = h2s[b][16 * m + (lane & 15)];
        } else {
            #pragma unroll
            for (int b = 0; b < NB; ++b)
                #pragma unroll
                for (int m = 0; m < 4; ++m)
                    hq1[b][m] = h1s[b][16 * m + (lane & 15)];
        }
    }

    // ---------------- FC epilogue: out[b] = dot(h2, Wfc) + bfc ----------------
    if (tid < 128) {
        const int b = tid >> 6;
        float v = h2s[b][lane] * Wfc[lane];
        #pragma unroll
        for (int off = 32; off > 0; off >>= 1)
            v += __shfl_down(v, off, 64);
        if (lane == 0) out[b0 + b] = v + bfc[0];
    }
}

} // namespace

extern "C" void kernel_launch(void* const* d_in, const int* in_sizes, int n_in,
                              void* d_out, int out_size, void* d_ws, size_t ws_size,
                              hipStream_t stream)
{
    const float* x    = (const float*)d_in[0];
    const float* Wih0 = (const float*)d_in[1];
    const float* Whh0 = (const float*)d_in[2];
    const float* bih0 = (const float*)d_in[3];
    const float* bhh0 = (const float*)d_in[4];
    const float* Wih1 = (const float*)d_in[5];
    const float* Whh1 = (const float*)d_in[6];
    const float* bih1 = (const float*)d_in[7];
    const float* bhh1 = (const float*)d_in[8];
    const float* Wfc  = (const float*)d_in[9];
    const float* bfc  = (const float*)d_in[10];
    float* out = (float*)d_out;

    hipLaunchKernelGGL(lstm_dpp, dim3(512 / NB), dim3(768), 0, stream,
                       x, Wih0, Whh0, bih0, bhh0, Wih1, Whh1, bih1, bhh1,
                       Wfc, bfc, out);
}

// Round 4
// 3923.526 us; speedup vs baseline: 1.4016x; 1.4016x over previous
//
#include <hip/hip_runtime.h>

namespace {

constexpr int H   = 64;
constexpr int NIN = 21;
constexpr int T   = 3000;
constexpr int NB  = 2;     // batches per block
constexpr int G   = 256;   // 4*H

__device__ __forceinline__ float sigm(float v) {
    return 1.0f / (1.0f + __expf(-v));
}
__device__ __forceinline__ float tanh_fast(float v) {
    float e = __expf(2.0f * v);
    return 1.0f - 2.0f / (e + 1.0f);
}

// One MAC = one VOP2 v_fmac_f32 with DPP row_ror on src0 (the h operand).
// HW: row_ror:J delivers in[(lane & 48) | ((lane - J) & 15)] — matches the
// (lane - j) & 15 weight gather (verified passing in round 3).
#define FMAC0(A, Hv, Wv) \
    asm("v_fmac_f32 %0, %2, %3" : "=v"(A) : "0"(A), "v"(Hv), "v"(Wv))
#define FMACJ(A, Hv, Wv, J) \
    asm("v_fmac_f32 %0, %2, %3 row_ror:" #J : "=v"(A) : "0"(A), "v"(Hv), "v"(Wv))

// 16-term rotated dot for both batches; 4 accumulator chains (even/odd J x batch)
#define DOT16(W, OFS, H0, H1, A0E, A0O, A1E, A1O) do {            \
    FMAC0(A0E, H0, W[OFS + 0]);      FMAC0(A1E, H1, W[OFS + 0]);  \
    FMACJ(A0O, H0, W[OFS + 1], 1);   FMACJ(A1O, H1, W[OFS + 1], 1);\
    FMACJ(A0E, H0, W[OFS + 2], 2);   FMACJ(A1E, H1, W[OFS + 2], 2);\
    FMACJ(A0O, H0, W[OFS + 3], 3);   FMACJ(A1O, H1, W[OFS + 3], 3);\
    FMACJ(A0E, H0, W[OFS + 4], 4);   FMACJ(A1E, H1, W[OFS + 4], 4);\
    FMACJ(A0O, H0, W[OFS + 5], 5);   FMACJ(A1O, H1, W[OFS + 5], 5);\
    FMACJ(A0E, H0, W[OFS + 6], 6);   FMACJ(A1E, H1, W[OFS + 6], 6);\
    FMACJ(A0O, H0, W[OFS + 7], 7);   FMACJ(A1O, H1, W[OFS + 7], 7);\
    FMACJ(A0E, H0, W[OFS + 8], 8);   FMACJ(A1E, H1, W[OFS + 8], 8);\
    FMACJ(A0O, H0, W[OFS + 9], 9);   FMACJ(A1O, H1, W[OFS + 9], 9);\
    FMACJ(A0E, H0, W[OFS + 10], 10); FMACJ(A1E, H1, W[OFS + 10], 10);\
    FMACJ(A0O, H0, W[OFS + 11], 11); FMACJ(A1O, H1, W[OFS + 11], 11);\
    FMACJ(A0E, H0, W[OFS + 12], 12); FMACJ(A1E, H1, W[OFS + 12], 12);\
    FMACJ(A0O, H0, W[OFS + 13], 13); FMACJ(A1O, H1, W[OFS + 13], 13);\
    FMACJ(A0E, H0, W[OFS + 14], 14); FMACJ(A1E, H1, W[OFS + 14], 14);\
    FMACJ(A0O, H0, W[OFS + 15], 15); FMACJ(A1O, H1, W[OFS + 15], 15);\
} while (0)

__launch_bounds__(768, 3)
__global__ void lstm_dpp(const float* __restrict__ x,
                         const float* __restrict__ Wih0, const float* __restrict__ Whh0,
                         const float* __restrict__ bih0, const float* __restrict__ bhh0,
                         const float* __restrict__ Wih1, const float* __restrict__ Whh1,
                         const float* __restrict__ bih1, const float* __restrict__ bhh1,
                         const float* __restrict__ Wfc,  const float* __restrict__ bfc,
                         float* __restrict__ out)
{
    const int tid  = threadIdx.x;
    const int lane = tid & 63;
    const int wid  = tid >> 6;
    const int b0   = blockIdx.x * NB;

    // roles: waves 0-3 = layer0 gate rows; 4-7 = Wih1 rows (+x staging);
    //        8-11 = Whh1 rows (+ ALL pointwise: 8-9 layer0, 10-11 layer1)
    const bool isA = (wid < 4);
    const bool isB = (wid >= 4 && wid < 8);
    const int  g   = tid & 255;        // gate row within role

    __shared__ float xs[4][NB][32];    // x staged 2 steps ahead, padded 21->32
    __shared__ float a0s[NB][G];       // layer0 pre-activations
    __shared__ float p1x[NB][G];       // layer1 Wih1*h1 partial
    __shared__ float p1h[NB][G];       // layer1 Whh1*h2 partial (+bias1)
    __shared__ float h1s[NB][H];
    __shared__ float h2s[NB][H];

    // ---- per-lane weight gather, permuted for the DPP access pattern ----
    // slot J must hold rowW[16m + ((lane - J) & 15)]  (row_ror semantics)
    float wH[64];
    float wX[32];
    float bias = 0.0f;
    {
        const float* rowH;
        if (isA)      rowH = Whh0 + g * 64;
        else if (isB) rowH = Wih1 + g * 64;
        else          rowH = Whh1 + g * 64;
        #pragma unroll
        for (int m = 0; m < 4; ++m)
            #pragma unroll
            for (int j = 0; j < 16; ++j)
                wH[m * 16 + j] = rowH[16 * m + ((lane - j) & 15)];

        if (isA) {
            #pragma unroll
            for (int m = 0; m < 2; ++m)
                #pragma unroll
                for (int j = 0; j < 16; ++j) {
                    int k = 16 * m + ((lane - j) & 15);
                    wX[m * 16 + j] = (k < NIN) ? Wih0[g * NIN + k] : 0.0f;
                }
            bias = bih0[g] + bhh0[g];
        } else {
            #pragma unroll
            for (int i = 0; i < 32; ++i) wX[i] = 0.0f;
            if (!isB) bias = bih1[g] + bhh1[g];
        }
    }

    // zero h buffers, stage x(t=0) and x(t=1)
    if (tid < NB * H) {
        (&h1s[0][0])[tid] = 0.0f;
        (&h2s[0][0])[tid] = 0.0f;
    }
    if ((wid == 4 || wid == 5) && lane < NIN)
        xs[0][wid - 4][lane] = x[((size_t)(b0 + (wid - 4)) * T + 0) * NIN + lane];
    if ((wid == 6 || wid == 7) && lane < NIN)
        xs[1][wid - 6][lane] = x[((size_t)(b0 + (wid - 6)) * T + 1) * NIN + lane];

    float hq1[NB][4];   // h1 replicated: hq1[b][m] = h1[b][16m + (lane&15)]
    float hq2[NB][4];
    #pragma unroll
    for (int b = 0; b < NB; ++b)
        #pragma unroll
        for (int m = 0; m < 4; ++m) { hq1[b][m] = 0.0f; hq2[b][m] = 0.0f; }

    float c_st = 0.0f;   // c-state: waves 8-9 -> layer0 c, waves 10-11 -> layer1 c
    __syncthreads();

    // Pipeline: iteration t computes layer0(t) and layer1(t-1).
    for (int t = 0; t <= T; ++t) {
        // ---------------- phase 1: matvec FMAs ----------------
        if (isA) {
            if (t < T) {
                float xq00 = xs[t & 3][0][lane & 15];
                float xq01 = xs[t & 3][0][16 + (lane & 15)];
                float xq10 = xs[t & 3][1][lane & 15];
                float xq11 = xs[t & 3][1][16 + (lane & 15)];
                float a0e = bias, a0o = 0.0f, a1e = bias, a1o = 0.0f;
                DOT16(wH, 0,  hq1[0][0], hq1[1][0], a0e, a0o, a1e, a1o);
                DOT16(wH, 16, hq1[0][1], hq1[1][1], a0e, a0o, a1e, a1o);
                DOT16(wH, 32, hq1[0][2], hq1[1][2], a0e, a0o, a1e, a1o);
                DOT16(wH, 48, hq1[0][3], hq1[1][3], a0e, a0o, a1e, a1o);
                DOT16(wX, 0,  xq00,      xq10,      a0e, a0o, a1e, a1o);
                DOT16(wX, 16, xq01,      xq11,      a0e, a0o, a1e, a1o);
                a0s[0][g] = a0e + a0o;
                a0s[1][g] = a1e + a1o;
            }
        } else if (isB) {
            // stage x(t+2) early; LDS-write after the FMAs (latency hidden)
            float xv = 0.0f;
            const int  bs = wid & 1;                       // wave4/6 -> b0, wave5/7 -> b1
            const bool st = (wid == 4 || wid == 5) && (t + 2 < T) && (lane < NIN);
            if (st) xv = x[((size_t)(b0 + bs) * T + (t + 2)) * NIN + lane];
            if (t > 0) {
                float a0e = 0.0f, a0o = 0.0f, a1e = 0.0f, a1o = 0.0f;
                DOT16(wH, 0,  hq1[0][0], hq1[1][0], a0e, a0o, a1e, a1o);
                DOT16(wH, 16, hq1[0][1], hq1[1][1], a0e, a0o, a1e, a1o);
                DOT16(wH, 32, hq1[0][2], hq1[1][2], a0e, a0o, a1e, a1o);
                DOT16(wH, 48, hq1[0][3], hq1[1][3], a0e, a0o, a1e, a1o);
                p1x[0][g] = a0e + a0o;
                p1x[1][g] = a1e + a1o;
            }
            if (st) xs[(t + 2) & 3][bs][lane] = xv;
        } else {
            if (t > 0) {
                float a0e = bias, a0o = 0.0f, a1e = bias, a1o = 0.0f;
                DOT16(wH, 0,  hq2[0][0], hq2[1][0], a0e, a0o, a1e, a1o);
                DOT16(wH, 16, hq2[0][1], hq2[1][1], a0e, a0o, a1e, a1o);
                DOT16(wH, 32, hq2[0][2], hq2[1][2], a0e, a0o, a1e, a1o);
                DOT16(wH, 48, hq2[0][3], hq2[1][3], a0e, a0o, a1e, a1o);
                p1h[0][g] = a0e + a0o;
                p1h[1][g] = a1e + a1o;
            }
        }
        __syncthreads();

        // ---------------- phase 2: pointwise (on the lightest waves, 8-11) ----------------
        if (wid == 8 || wid == 9) {
            if (t < T) {                       // layer0 step t
                const int b = wid - 8;
                const int u = lane;
                float gi = a0s[b][u];
                float gf = a0s[b][64 + u];
                float gg = a0s[b][128 + u];
                float go = a0s[b][192 + u];
                float i_ = sigm(gi), f_ = sigm(gf), g_ = tanh_fast(gg), o_ = sigm(go);
                c_st = fmaf(f_, c_st, i_ * g_);
                h1s[b][u] = o_ * tanh_fast(c_st);
            }
        } else if (wid == 10 || wid == 11) {
            if (t > 0) {                       // layer1 step t-1
                const int b = wid - 10;
                const int u = lane;
                float gi = p1x[b][u]       + p1h[b][u];
                float gf = p1x[b][64 + u]  + p1h[b][64 + u];
                float gg = p1x[b][128 + u] + p1h[b][128 + u];
                float go = p1x[b][192 + u] + p1h[b][192 + u];
                float i_ = sigm(gi), f_ = sigm(gf), g_ = tanh_fast(gg), o_ = sigm(go);
                c_st = fmaf(f_, c_st, i_ * g_);
                h2s[b][u] = o_ * tanh_fast(c_st);
            }
        }
        __syncthreads();

        if (t == T) break;

        // ---------------- phase 3: redistribute h into rotation registers ----------------
        if (wid >= 8) {
            #pragma unroll
            for (int b = 0; b < NB; ++b)
                #pragma unroll
                for (int m = 0; m < 4; ++m)
                    hq2[b][m] = h2s[b][16 * m + (lane & 15)];
        } else {
            #pragma unroll
            for (int b = 0; b < NB; ++b)
                #pragma unroll
                for (int m = 0; m < 4; ++m)
                    hq1[b][m] = h1s[b][16 * m + (lane & 15)];
        }
    }

    // ---------------- FC epilogue: out[b] = dot(h2, Wfc) + bfc ----------------
    if (tid < 128) {
        const int b = tid >> 6;
        float v = h2s[b][lane] * Wfc[lane];
        #pragma unroll
        for (int off = 32; off > 0; off >>= 1)
            v += __shfl_down(v, off, 64);
        if (lane == 0) out[b0 + b] = v + bfc[0];
    }
}

} // namespace

extern "C" void kernel_launch(void* const* d_in, const int* in_sizes, int n_in,
                              void* d_out, int out_size, void* d_ws, size_t ws_size,
                              hipStream_t stream)
{
    const float* x    = (const float*)d_in[0];
    const float* Wih0 = (const float*)d_in[1];
    const float* Whh0 = (const float*)d_in[2];
    const float* bih0 = (const float*)d_in[3];
    const float* bhh0 = (const float*)d_in[4];
    const float* Wih1 = (const float*)d_in[5];
    const float* Whh1 = (const float*)d_in[6];
    const float* bih1 = (const float*)d_in[7];
    const float* bhh1 = (const float*)d_in[8];
    const float* Wfc  = (const float*)d_in[9];
    const float* bfc  = (const float*)d_in[10];
    float* out = (float*)d_out;

    hipLaunchKernelGGL(lstm_dpp, dim3(512 / NB), dim3(768), 0, stream,
                       x, Wih0, Whh0, bih0, bhh0, Wih1, Whh1, bih1, bhh1,
                       Wfc, bfc, out);
}

// Round 5
// 3901.098 us; speedup vs baseline: 1.4096x; 1.0057x over previous
//
#include <hip/hip_runtime.h>

namespace {

constexpr int H   = 64;
constexpr int NIN = 21;
constexpr int T   = 3000;
constexpr int NB  = 2;     // batches per block
constexpr int G   = 256;   // 4*H

__device__ __forceinline__ float sigm(float v) {
    return 1.0f / (1.0f + __expf(-v));
}
__device__ __forceinline__ float tanh_fast(float v) {
    float e = __expf(2.0f * v);
    return 1.0f - 2.0f / (e + 1.0f);
}

// One MAC = one VOP2 v_fmac_f32 with DPP row_ror on src0 (the h operand).
// HW: row_ror:J delivers in[(lane & 48) | ((lane - J) & 15)] — matches the
// (lane - j) & 15 weight gather (verified passing in rounds 3/4).
#define FMAC0(A, Hv, Wv) \
    asm("v_fmac_f32 %0, %2, %3" : "=v"(A) : "0"(A), "v"(Hv), "v"(Wv))
#define FMACJ(A, Hv, Wv, J) \
    asm("v_fmac_f32 %0, %2, %3 row_ror:" #J : "=v"(A) : "0"(A), "v"(Hv), "v"(Wv))

// 16-term rotated dot for both batches; 4 accumulator chains (even/odd J x batch)
#define DOT16(W, OFS, H0, H1, A0E, A0O, A1E, A1O) do {            \
    FMAC0(A0E, H0, W[OFS + 0]);      FMAC0(A1E, H1, W[OFS + 0]);  \
    FMACJ(A0O, H0, W[OFS + 1], 1);   FMACJ(A1O, H1, W[OFS + 1], 1);\
    FMACJ(A0E, H0, W[OFS + 2], 2);   FMACJ(A1E, H1, W[OFS + 2], 2);\
    FMACJ(A0O, H0, W[OFS + 3], 3);   FMACJ(A1O, H1, W[OFS + 3], 3);\
    FMACJ(A0E, H0, W[OFS + 4], 4);   FMACJ(A1E, H1, W[OFS + 4], 4);\
    FMACJ(A0O, H0, W[OFS + 5], 5);   FMACJ(A1O, H1, W[OFS + 5], 5);\
    FMACJ(A0E, H0, W[OFS + 6], 6);   FMACJ(A1E, H1, W[OFS + 6], 6);\
    FMACJ(A0O, H0, W[OFS + 7], 7);   FMACJ(A1O, H1, W[OFS + 7], 7);\
    FMACJ(A0E, H0, W[OFS + 8], 8);   FMACJ(A1E, H1, W[OFS + 8], 8);\
    FMACJ(A0O, H0, W[OFS + 9], 9);   FMACJ(A1O, H1, W[OFS + 9], 9);\
    FMACJ(A0E, H0, W[OFS + 10], 10); FMACJ(A1E, H1, W[OFS + 10], 10);\
    FMACJ(A0O, H0, W[OFS + 11], 11); FMACJ(A1O, H1, W[OFS + 11], 11);\
    FMACJ(A0E, H0, W[OFS + 12], 12); FMACJ(A1E, H1, W[OFS + 12], 12);\
    FMACJ(A0O, H0, W[OFS + 13], 13); FMACJ(A1O, H1, W[OFS + 13], 13);\
    FMACJ(A0E, H0, W[OFS + 14], 14); FMACJ(A1E, H1, W[OFS + 14], 14);\
    FMACJ(A0O, H0, W[OFS + 15], 15); FMACJ(A1O, H1, W[OFS + 15], 15);\
} while (0)

// grid == 256 == #CUs: exactly one persistent block per CU, so extra
// occupancy is impossible — give the allocator the full 512-reg budget
// so the 96 weight floats stay in ARCH VGPRs (no AGPR shuttle copies).
__launch_bounds__(768, 1)
__global__ void lstm_dpp(const float* __restrict__ x,
                         const float* __restrict__ Wih0, const float* __restrict__ Whh0,
                         const float* __restrict__ bih0, const float* __restrict__ bhh0,
                         const float* __restrict__ Wih1, const float* __restrict__ Whh1,
                         const float* __restrict__ bih1, const float* __restrict__ bhh1,
                         const float* __restrict__ Wfc,  const float* __restrict__ bfc,
                         float* __restrict__ out)
{
    const int tid  = threadIdx.x;
    const int lane = tid & 63;
    const int wid  = tid >> 6;
    const int b0   = blockIdx.x * NB;

    // roles: waves 0-3 = layer0 gate rows; 4-7 = Wih1 rows (+x staging);
    //        8-11 = Whh1 rows (+ ALL pointwise: 8-9 layer0, 10-11 layer1)
    const bool isA = (wid < 4);
    const bool isB = (wid >= 4 && wid < 8);
    const int  g   = tid & 255;        // gate row within role

    __shared__ float xs[4][NB][32];    // x staged 2 steps ahead, padded 21->32
    __shared__ float a0s[NB][G];       // layer0 pre-activations
    __shared__ float p1x[NB][G];       // layer1 Wih1*h1 partial
    __shared__ float p1h[NB][G];       // layer1 Whh1*h2 partial (+bias1)
    __shared__ float h1s[NB][H];
    __shared__ float h2s[NB][H];

    // ---- per-lane weight gather, permuted for the DPP access pattern ----
    // slot J must hold rowW[16m + ((lane - J) & 15)]  (row_ror semantics)
    float wH[64];
    float wX[32];
    float bias = 0.0f;
    {
        const float* rowH;
        if (isA)      rowH = Whh0 + g * 64;
        else if (isB) rowH = Wih1 + g * 64;
        else          rowH = Whh1 + g * 64;
        #pragma unroll
        for (int m = 0; m < 4; ++m)
            #pragma unroll
            for (int j = 0; j < 16; ++j)
                wH[m * 16 + j] = rowH[16 * m + ((lane - j) & 15)];

        if (isA) {
            #pragma unroll
            for (int m = 0; m < 2; ++m)
                #pragma unroll
                for (int j = 0; j < 16; ++j) {
                    int k = 16 * m + ((lane - j) & 15);
                    wX[m * 16 + j] = (k < NIN) ? Wih0[g * NIN + k] : 0.0f;
                }
            bias = bih0[g] + bhh0[g];
        } else {
            #pragma unroll
            for (int i = 0; i < 32; ++i) wX[i] = 0.0f;
            if (!isB) bias = bih1[g] + bhh1[g];
        }
    }

    // zero h buffers, stage x(t=0) and x(t=1)
    if (tid < NB * H) {
        (&h1s[0][0])[tid] = 0.0f;
        (&h2s[0][0])[tid] = 0.0f;
    }
    if ((wid == 4 || wid == 5) && lane < NIN)
        xs[0][wid - 4][lane] = x[((size_t)(b0 + (wid - 4)) * T + 0) * NIN + lane];
    if ((wid == 6 || wid == 7) && lane < NIN)
        xs[1][wid - 6][lane] = x[((size_t)(b0 + (wid - 6)) * T + 1) * NIN + lane];

    float hq1[NB][4];   // h1 replicated: hq1[b][m] = h1[b][16m + (lane&15)]
    float hq2[NB][4];
    #pragma unroll
    for (int b = 0; b < NB; ++b)
        #pragma unroll
        for (int m = 0; m < 4; ++m) { hq1[b][m] = 0.0f; hq2[b][m] = 0.0f; }

    float c_st = 0.0f;   // c-state: waves 8-9 -> layer0 c, waves 10-11 -> layer1 c
    __syncthreads();

    // Pipeline: iteration t computes layer0(t) and layer1(t-1).
    for (int t = 0; t <= T; ++t) {
        // ---------------- phase 1: matvec FMAs ----------------
        if (isA) {
            if (t < T) {
                float xq00 = xs[t & 3][0][lane & 15];
                float xq01 = xs[t & 3][0][16 + (lane & 15)];
                float xq10 = xs[t & 3][1][lane & 15];
                float xq11 = xs[t & 3][1][16 + (lane & 15)];
                float a0e = bias, a0o = 0.0f, a1e = bias, a1o = 0.0f;
                DOT16(wH, 0,  hq1[0][0], hq1[1][0], a0e, a0o, a1e, a1o);
                DOT16(wH, 16, hq1[0][1], hq1[1][1], a0e, a0o, a1e, a1o);
                DOT16(wH, 32, hq1[0][2], hq1[1][2], a0e, a0o, a1e, a1o);
                DOT16(wH, 48, hq1[0][3], hq1[1][3], a0e, a0o, a1e, a1o);
                DOT16(wX, 0,  xq00,      xq10,      a0e, a0o, a1e, a1o);
                DOT16(wX, 16, xq01,      xq11,      a0e, a0o, a1e, a1o);
                a0s[0][g] = a0e + a0o;
                a0s[1][g] = a1e + a1o;
            }
        } else if (isB) {
            // stage x(t+2) early; LDS-write after the FMAs (latency hidden)
            float xv = 0.0f;
            const int  bs = wid & 1;                       // wave4/6 -> b0, wave5/7 -> b1
            const bool st = (wid == 4 || wid == 5) && (t + 2 < T) && (lane < NIN);
            if (st) xv = x[((size_t)(b0 + bs) * T + (t + 2)) * NIN + lane];
            if (t > 0) {
                float a0e = 0.0f, a0o = 0.0f, a1e = 0.0f, a1o = 0.0f;
                DOT16(wH, 0,  hq1[0][0], hq1[1][0], a0e, a0o, a1e, a1o);
                DOT16(wH, 16, hq1[0][1], hq1[1][1], a0e, a0o, a1e, a1o);
                DOT16(wH, 32, hq1[0][2], hq1[1][2], a0e, a0o, a1e, a1o);
                DOT16(wH, 48, hq1[0][3], hq1[1][3], a0e, a0o, a1e, a1o);
                p1x[0][g] = a0e + a0o;
                p1x[1][g] = a1e + a1o;
            }
            if (st) xs[(t + 2) & 3][bs][lane] = xv;
        } else {
            if (t > 0) {
                float a0e = bias, a0o = 0.0f, a1e = bias, a1o = 0.0f;
                DOT16(wH, 0,  hq2[0][0], hq2[1][0], a0e, a0o, a1e, a1o);
                DOT16(wH, 16, hq2[0][1], hq2[1][1], a0e, a0o, a1e, a1o);
                DOT16(wH, 32, hq2[0][2], hq2[1][2], a0e, a0o, a1e, a1o);
                DOT16(wH, 48, hq2[0][3], hq2[1][3], a0e, a0o, a1e, a1o);
                p1h[0][g] = a0e + a0o;
                p1h[1][g] = a1e + a1o;
            }
        }
        __syncthreads();

        // ---------------- phase 2: pointwise (on the lightest waves, 8-11) ----------------
        if (wid == 8 || wid == 9) {
            if (t < T) {                       // layer0 step t
                const int b = wid - 8;
                const int u = lane;
                float gi = a0s[b][u];
                float gf = a0s[b][64 + u];
                float gg = a0s[b][128 + u];
                float go = a0s[b][192 + u];
                float i_ = sigm(gi), f_ = sigm(gf), g_ = tanh_fast(gg), o_ = sigm(go);
                c_st = fmaf(f_, c_st, i_ * g_);
                h1s[b][u] = o_ * tanh_fast(c_st);
            }
        } else if (wid == 10 || wid == 11) {
            if (t > 0) {                       // layer1 step t-1
                const int b = wid - 10;
                const int u = lane;
                float gi = p1x[b][u]       + p1h[b][u];
                float gf = p1x[b][64 + u]  + p1h[b][64 + u];
                float gg = p1x[b][128 + u] + p1h[b][128 + u];
                float go = p1x[b][192 + u] + p1h[b][192 + u];
                float i_ = sigm(gi), f_ = sigm(gf), g_ = tanh_fast(gg), o_ = sigm(go);
                c_st = fmaf(f_, c_st, i_ * g_);
                h2s[b][u] = o_ * tanh_fast(c_st);
            }
        }
        __syncthreads();

        if (t == T) break;

        // ---------------- phase 3: redistribute h into rotation registers ----------------
        if (wid >= 8) {
            #pragma unroll
            for (int b = 0; b < NB; ++b)
                #pragma unroll
                for (int m = 0; m < 4; ++m)
                    hq2[b][m] = h2s[b][16 * m + (lane & 15)];
        } else {
            #pragma unroll
            for (int b = 0; b < NB; ++b)
                #pragma unroll
                for (int m = 0; m < 4; ++m)
                    hq1[b][m] = h1s[b][16 * m + (lane & 15)];
        }
    }

    // ---------------- FC epilogue: out[b] = dot(h2, Wfc) + bfc ----------------
    if (tid < 128) {
        const int b = tid >> 6;
        float v = h2s[b][lane] * Wfc[lane];
        #pragma unroll
        for (int off = 32; off > 0; off >>= 1)
            v += __shfl_down(v, off, 64);
        if (lane == 0) out[b0 + b] = v + bfc[0];
    }
}

} // namespace

extern "C" void kernel_launch(void* const* d_in, const int* in_sizes, int n_in,
                              void* d_out, int out_size, void* d_ws, size_t ws_size,
                              hipStream_t stream)
{
    const float* x    = (const float*)d_in[0];
    const float* Wih0 = (const float*)d_in[1];
    const float* Whh0 = (const float*)d_in[2];
    const float* bih0 = (const float*)d_in[3];
    const float* bhh0 = (const float*)d_in[4];
    const float* Wih1 = (const float*)d_in[5];
    const float* Whh1 = (const float*)d_in[6];
    const float* bih1 = (const float*)d_in[7];
    const float* bhh1 = (const float*)d_in[8];
    const float* Wfc  = (const float*)d_in[9];
    const float* bfc  = (const float*)d_in[10];
    float* out = (float*)d_out;

    hipLaunchKernelGGL(lstm_dpp, dim3(512 / NB), dim3(768), 0, stream,
                       x, Wih0, Whh0, bih0, bhh0, Wih1, Whh1, bih1, bhh1,
                       Wfc, bfc, out);
}